// Round 16
// baseline (158.700 us; speedup 1.0000x reference)
//
#include <hip/hip_runtime.h>
#include <cstdint>

constexpr int Sd = 1024;
constexpr int Td = 48;
constexpr int NTAG = 45;    // normal tags 0..44
constexpr int START_ = 45;
constexpr int STOP_ = 46;

__device__ __forceinline__ int rfl_i(int x) { return __builtin_amdgcn_readfirstlane(x); }

// DPP-fused MAC: acc += rot(s, N) * ee   (rotation folded into the FMA)
#define FMD(acc, s, ee, N) \
    asm("v_fmac_f32 %0, %1, %2 row_ror:" #N " row_mask:0xf bank_mask:0xf" \
        : "+v"(acc) : "v"(s), "v"(ee))
// DPP-fused MUL (chain init): acc = rot(s, N) * ee
#define MULD(acc, s, ee, N) \
    asm("v_mul_f32 %0, %1, %2 row_ror:" #N " row_mask:0xf bank_mask:0xf" \
        : "=v"(acc) : "v"(s), "v"(ee))

// 16 rotations of one slot dotted with its E block; two 8-deep chains
#define SLOT16(s, E, aA, aB) do {                                              \
    aA = (s) * E[0];                                                           \
    FMD(aA, s, E[1], 1);  FMD(aA, s, E[2], 2);  FMD(aA, s, E[3], 3);           \
    FMD(aA, s, E[4], 4);  FMD(aA, s, E[5], 5);  FMD(aA, s, E[6], 6);           \
    FMD(aA, s, E[7], 7);                                                       \
    MULD(aB, s, E[8], 8);                                                      \
    FMD(aB, s, E[9], 9);  FMD(aB, s, E[10], 10); FMD(aB, s, E[11], 11);        \
    FMD(aB, s, E[12], 12); FMD(aB, s, E[13], 13); FMD(aB, s, E[14], 14);       \
    FMD(aB, s, E[15], 15);                                                     \
} while (0)

// One exp-domain chain step (R12-validated, ~57 VALU instrs):
//   slot0 = v; slot1/2 = ds_bpermute v[(lane+16/32)%48]
//   48 DPP-fused MACs vs eA0/eA1/eA2 (register-resident, compile-time indexed)
//   PF holds PRE-EXP'd emission; scalar power-of-2 renorm (R5..R12-validated)
#define STEP1(PF) do {                                                         \
    int _vi = __float_as_int(v);                                               \
    int _b1 = __builtin_amdgcn_ds_bpermute(a16, _vi);                          \
    int _b2 = __builtin_amdgcn_ds_bpermute(a32, _vi);                          \
    float _s1 = __int_as_float(_b1), _s2 = __int_as_float(_b2);                \
    float a0A, a0B, a1A, a1B, a2A, a2B;                                        \
    SLOT16(v,   eA0, a0A, a0B);                                                \
    SLOT16(_s1, eA1, a1A, a1B);                                                \
    SLOT16(_s2, eA2, a2A, a2B);                                                \
    float tot_ = ((a0A + a0B) + (a1A + a1B)) + (a2A + a2B);                    \
    L += kx;                                                                   \
    uf = tot_ * sc;                                                            \
    v  = tot_ * ((PF) * sc);                                                   \
    { int _kb = rfl_i(__float_as_int(v));                                      \
      kx = ((_kb >> 23) & 0xFF) - 127;                                         \
      sc = __int_as_float((127 - kx) << 23); }                                 \
} while (0)

#define ADVP() do {                                                            \
    bool ok_ = isb ? (tn > 0) : (tn < tmax);                                   \
    pcur += ok_ ? sAdv : 0;                                                    \
    tn   += ok_ ? sInc : 0;                                                    \
} while (0)

__launch_bounds__(64, 1)
__global__ void crf_chains(const float* __restrict__ feats,
                           const float* __restrict__ masks,
                           const int* __restrict__ tags,
                           const float* __restrict__ trans,
                           float* __restrict__ wsv,   // [48][Bn] fwd meeting vec
                           float* __restrict__ wsu,   // [48][Bn] bwd meeting vec
                           int* __restrict__ wsLF, int* __restrict__ wsLB,
                           float* __restrict__ wsg,   // [Bn] gold
                           int Bn)
{
    __shared__ float tl[Td * Td];
    const int lane = threadIdx.x;
    const bool isb = ((int)blockIdx.x >= Bn);        // block-uniform direction
    const int b = isb ? ((int)blockIdx.x - Bn) : (int)blockIdx.x;

    for (int i = lane; i < Td * Td; i += 64) tl[i] = trans[i];
    __syncthreads();

    const size_t bS = (size_t)b * Sd;

    // ---- length from prefix mask (scalar) ----
    float c = 0.f;
    for (int t = lane; t < Sd; t += 64) c += masks[bS + t];
#pragma unroll
    for (int off = 32; off; off >>= 1) c += __shfl_xor(c, off);
    int len = (int)(c + 0.5f);
    if (len < 1) len = 1;
    len = rfl_i(len);

    // ---- gold score (fwd blocks only) ----
    if (!isb) {
        float g = 0.f;
        for (int t = lane; t < len; t += 64) {
            const int tag  = tags[bS + t];
            const int prev = (t == 0) ? START_ : tags[bS + t - 1];
            g += feats[(bS + t) * Td + tag] + tl[tag * Td + prev];
        }
#pragma unroll
        for (int off = 32; off; off >>= 1) g += __shfl_xor(g, off);
        g += tl[STOP_ * Td + tags[bS + len - 1]];
        if (lane == 0) wsg[b] = g;
    }

    // ---- runtime-detect row_ror direction (validated R9-R12) ----
    const int p = lane & 15;
    const int qd = __builtin_amdgcn_mov_dpp(p, 0x121, 0xF, 0xF, false); // row_ror:1
    const int d = (qd == ((p + 1) & 15)) ? 1 : -1;
    const int r0 = (lane >> 4) & 3;                  // own 16-block (3 = idle lanes)

    // ---- bpermute byte-addresses for the 3-block rotation gather ----
    const int a16 = (((lane + 16) % Td) << 2);       // pull v[(lane+16)%48]
    const int a32 = (((lane + 32) % Td) << 2);       // pull v[(lane+32)%48]

    // ---- E (fwd) / E^T (bwd), gather-permuted order, 48 regs ----
    // DEALIASED: no pointer-select over the arrays (that pattern demoted the
    // arrays out of VGPRs in R9-R15 -> 48 hidden rematerializations/step).
    // Every index below is compile-time after unroll.
    float eA0[16], eA1[16], eA2[16];
    {
        const int blk0 = 16 * ((r0 + 0) % 3);
        const int blk1 = 16 * ((r0 + 1) % 3);
        const int blk2 = 16 * ((r0 + 2) % 3);
        const bool okF = (lane < NTAG);              // fwd rows >= 45 are exact sinks
        const bool okU = (lane < Td);
#pragma unroll
        for (int i = 0; i < 16; ++i) {
            const int rr = (p + d * i) & 15;
            const int c0 = blk0 + rr, c1 = blk1 + rr, c2 = blk2 + rr;
            if (!isb) {
                eA0[i] = okF ? __expf(tl[lane * Td + c0]) : 0.f;
                eA1[i] = okF ? __expf(tl[lane * Td + c1]) : 0.f;
                eA2[i] = okF ? __expf(tl[lane * Td + c2]) : 0.f;
            } else {
                eA0[i] = okU ? __expf(tl[c0 * Td + lane]) : 0.f;
                eA1[i] = okU ? __expf(tl[c1 * Td + lane]) : 0.f;
                eA2[i] = okU ? __expf(tl[c2 * Td + lane]) : 0.f;
            }
        }
    }

    // ---- chain init ----
    const int lidx = (lane < Td) ? lane : 0;
    const float* frow = feats + bS * Td;
    const int Fh = (len + 1) >> 1;
    const int act = rfl_i(isb ? (len - Fh) : (Fh - 1));
    const int it0 = isb ? (len - 1) : 0;

    float einit;
    if (!isb) einit = (lane < NTAG) ? __expf(tl[lane * Td + START_]) : 0.f;
    else      einit = (lane < Td)   ? __expf(tl[STOP_ * Td + lane])  : 0.f;

    float v  = __expf(frow[(size_t)it0 * Td + lidx]) * einit;
    float uf = einit;                 // bwd act==0 case: wstop
    int L = 0, kx; float sc;
    { int kb = rfl_i(__float_as_int(v)); kx = ((kb >> 23) & 0xFF) - 127;
      sc = __int_as_float((127 - kx) << 23); }

    // ---- emission prefetch: 8 slots, PRE-EXP'd; uniform ptr + scalar advance ----
    auto eidx0 = [&](int s) -> int {
        if (!isb) { int t = 1 + s; return t < Sd ? t : (Sd - 1); }
        int t = len - 2 - s; return t > 0 ? t : 0;
    };
    float pf0 = __expf(frow[(size_t)eidx0(0) * Td + lidx]);
    float pf1 = __expf(frow[(size_t)eidx0(1) * Td + lidx]);
    float pf2 = __expf(frow[(size_t)eidx0(2) * Td + lidx]);
    float pf3 = __expf(frow[(size_t)eidx0(3) * Td + lidx]);
    float pf4 = __expf(frow[(size_t)eidx0(4) * Td + lidx]);
    float pf5 = __expf(frow[(size_t)eidx0(5) * Td + lidx]);
    float pf6 = __expf(frow[(size_t)eidx0(6) * Td + lidx]);
    float pf7 = __expf(frow[(size_t)eidx0(7) * Td + lidx]);
    int tn = eidx0(8);
    const float* pcur = frow + (size_t)tn * Td;
    const int sAdv = isb ? -Td : Td;
    const int sInc = isb ? -1 : 1;
    const int tmax = Sd - 1;

    int s = 0;
    while (s + 8 <= act) {
        STEP1(pf0); pf0 = __expf(pcur[lidx]); ADVP();
        STEP1(pf1); pf1 = __expf(pcur[lidx]); ADVP();
        STEP1(pf2); pf2 = __expf(pcur[lidx]); ADVP();
        STEP1(pf3); pf3 = __expf(pcur[lidx]); ADVP();
        STEP1(pf4); pf4 = __expf(pcur[lidx]); ADVP();
        STEP1(pf5); pf5 = __expf(pcur[lidx]); ADVP();
        STEP1(pf6); pf6 = __expf(pcur[lidx]); ADVP();
        STEP1(pf7); pf7 = __expf(pcur[lidx]); ADVP();
        s += 8;
    }
    if (s < act) { STEP1(pf0); ++s; }
    if (s < act) { STEP1(pf1); ++s; }
    if (s < act) { STEP1(pf2); ++s; }
    if (s < act) { STEP1(pf3); ++s; }
    if (s < act) { STEP1(pf4); ++s; }
    if (s < act) { STEP1(pf5); ++s; }
    if (s < act) { STEP1(pf6); ++s; }

    // ---- publish meeting pieces (component-major for coalesced combine) ----
    if (!isb) {
        if (lane < Td) wsv[lane * Bn + b] = v;
        if (lane == 0) wsLF[b] = L;
    } else {
        if (lane < Td) wsu[lane * Bn + b] = uf;
        if (lane == 0) wsLB[b] = L;
    }
}

__launch_bounds__(64)
__global__ void crf_combine(const float* __restrict__ wsv,
                            const float* __restrict__ wsu,
                            const int* __restrict__ wsLF,
                            const int* __restrict__ wsLB,
                            const float* __restrict__ wsg,
                            float* __restrict__ out, int Bn)
{
    const int b = blockIdx.x * 64 + threadIdx.x;
    if (b >= Bn) return;
    float dot = 0.f;
#pragma unroll
    for (int j = 0; j < Td; ++j)
        dot += wsv[j * Bn + b] * wsu[j * Bn + b];
    const float ln2 = 0.6931471805599453f;
    out[b] = (float)(wsLF[b] + wsLB[b]) * ln2 + __logf(dot) - wsg[b];
}

extern "C" void kernel_launch(void* const* d_in, const int* in_sizes, int n_in,
                              void* d_out, int out_size, void* d_ws, size_t ws_size,
                              hipStream_t stream) {
    const float* feats = (const float*)d_in[0];
    const float* masks = (const float*)d_in[1];
    const int*   tags  = (const int*)d_in[2];
    const float* trans = (const float*)d_in[3];
    float* outp = (float*)d_out;

    const int Bn = in_sizes[1] / Sd;                 // B = 512

    float* wsv  = (float*)d_ws;                      // [48][Bn]
    float* wsu  = wsv + (size_t)Td * Bn;             // [48][Bn]
    int*   wsLF = (int*)(wsu + (size_t)Td * Bn);     // [Bn]
    int*   wsLB = wsLF + Bn;                         // [Bn]
    float* wsg  = (float*)(wsLB + Bn);               // [Bn]

    crf_chains<<<dim3(2 * Bn), dim3(64), 0, stream>>>(feats, masks, tags, trans,
                                                      wsv, wsu, wsLF, wsLB, wsg, Bn);
    crf_combine<<<dim3((Bn + 63) / 64), dim3(64), 0, stream>>>(wsv, wsu, wsLF, wsLB, wsg, outp, Bn);
}

// Round 17
// 124.537 us; speedup vs baseline: 1.2743x; 1.2743x over previous
//
#include <hip/hip_runtime.h>
#include <cstdint>

constexpr int Sd = 1024;
constexpr int Td = 48;
constexpr int NTAG = 45;    // normal tags 0..44
constexpr int START_ = 45;
constexpr int STOP_ = 46;

__device__ __forceinline__ int rfl_i(int x) { return __builtin_amdgcn_readfirstlane(x); }

#define SWAP32(x, y) asm("v_permlane32_swap_b32 %0, %1" : "+v"(x), "+v"(y))
#define SWAP16(x, y) asm("v_permlane16_swap_b32 %0, %1" : "+v"(x), "+v"(y))

// DPP-fused MAC / MUL (non-volatile: scheduler free to interleave)
#define FMD(acc, s, ee, N) \
    asm("v_fmac_f32 %0, %1, %2 row_ror:" #N " row_mask:0xf bank_mask:0xf" \
        : "+v"(acc) : "v"(s), "v"(ee))
#define MULD(acc, s, ee, N) \
    asm("v_mul_f32 %0, %1, %2 row_ror:" #N " row_mask:0xf bank_mask:0xf" \
        : "=v"(acc) : "v"(s), "v"(ee))

// 16 rotations of one slot vs its E block; FOUR 4-deep chains (short path)
#define SLOT4(s, E, c0, c1, c2, c3) do {                                       \
    c0 = (s) * E[0];                                                           \
    MULD(c1, s, E[1], 1);  MULD(c2, s, E[2], 2);  MULD(c3, s, E[3], 3);        \
    FMD(c0, s, E[4], 4);   FMD(c1, s, E[5], 5);   FMD(c2, s, E[6], 6);         \
    FMD(c3, s, E[7], 7);   FMD(c0, s, E[8], 8);   FMD(c1, s, E[9], 9);         \
    FMD(c2, s, E[10], 10); FMD(c3, s, E[11], 11); FMD(c0, s, E[12], 12);       \
    FMD(c1, s, E[13], 13); FMD(c2, s, E[14], 14); FMD(c3, s, E[15], 15);       \
} while (0)

// all-VALU gather (R10/R15-validated): swap32 self + swap16 self -> four
// full-wave dups of the 16-blocks; q-mask cndmask selects blocks (g+1)%3,(g+2)%3
#define GATH()                                                                 \
    int _A = __float_as_int(v), _B = __float_as_int(v);                        \
    SWAP32(_A, _B);                                                            \
    int _S0 = _A, _S1 = _A; SWAP16(_S0, _S1);                                  \
    int _S2 = _B, _S3 = _B; SWAP16(_S2, _S3);                                  \
    float _f0 = __int_as_float(_S0), _f1 = __int_as_float(_S1);                \
    float _f2 = __int_as_float(_S2), _f3 = __int_as_float(_S3);                \
    float _x1 = _f0; _x1 = q11 ? _f1 : _x1; _x1 = q12 ? _f2 : _x1;             \
    _x1 = q13 ? _f3 : _x1;                                                     \
    float _x2 = _f0; _x2 = q21 ? _f1 : _x2; _x2 = q22 ? _f2 : _x2;             \
    _x2 = q23 ? _f3 : _x2;                                                     \
    float c00,c01,c02,c03,c10,c11,c12,c13,c20,c21,c22,c23;                     \
    SLOT4(v,   eA0, c00, c01, c02, c03);                                       \
    SLOT4(_x1, eA1, c10, c11, c12, c13);                                       \
    SLOT4(_x2, eA2, c20, c21, c22, c23);                                       \
    float tot_ = (((c00 + c01) + (c02 + c03)) + ((c10 + c11) + (c12 + c13)))   \
               + ((c20 + c21) + (c22 + c23))

// LIGHT step: no renorm applied (sc-correction deferred; exact power-of-2 math)
#define STEP_L(PF) do {                                                        \
    GATH();                                                                    \
    uf = tot_;                                                                 \
    v  = tot_ * (PF);                                                          \
} while (0)

// HEAVY step: applies pending scale sc (exact), accounts L, recomputes kx/sc
#define STEP_H(PF) do {                                                        \
    GATH();                                                                    \
    L += kx;                                                                   \
    uf = tot_ * sc;                                                            \
    v  = tot_ * ((PF) * sc);                                                   \
    { int _kb = rfl_i(__float_as_int(v));                                      \
      kx = ((_kb >> 23) & 0xFF) - 127;                                         \
      sc = __int_as_float((127 - kx) << 23); }                                 \
} while (0)

#define ADVP() do {                                                            \
    bool ok_ = isb ? (tn > 0) : (tn < tmax);                                   \
    pcur += ok_ ? sAdv : 0;                                                    \
    tn   += ok_ ? sInc : 0;                                                    \
} while (0)

__launch_bounds__(64, 1)
__global__ void crf_chains(const float* __restrict__ feats,
                           const float* __restrict__ masks,
                           const int* __restrict__ tags,
                           const float* __restrict__ trans,
                           float* __restrict__ wsv,   // [48][Bn] fwd meeting vec
                           float* __restrict__ wsu,   // [48][Bn] bwd meeting vec
                           int* __restrict__ wsLF, int* __restrict__ wsLB,
                           float* __restrict__ wsg,   // [Bn] gold
                           int Bn)
{
    __shared__ float tl[Td * Td];
    const int lane = threadIdx.x;
    const bool isb = ((int)blockIdx.x >= Bn);        // block-uniform direction
    const int b = isb ? ((int)blockIdx.x - Bn) : (int)blockIdx.x;

    for (int i = lane; i < Td * Td; i += 64) tl[i] = trans[i];
    __syncthreads();

    const size_t bS = (size_t)b * Sd;

    // ---- length from prefix mask (scalar) ----
    float c = 0.f;
    for (int t = lane; t < Sd; t += 64) c += masks[bS + t];
#pragma unroll
    for (int off = 32; off; off >>= 1) c += __shfl_xor(c, off);
    int len = (int)(c + 0.5f);
    if (len < 1) len = 1;
    len = rfl_i(len);

    // ---- gold score (fwd blocks only) ----
    if (!isb) {
        float g = 0.f;
        for (int t = lane; t < len; t += 64) {
            const int tag  = tags[bS + t];
            const int prev = (t == 0) ? START_ : tags[bS + t - 1];
            g += feats[(bS + t) * Td + tag] + tl[tag * Td + prev];
        }
#pragma unroll
        for (int off = 32; off; off >>= 1) g += __shfl_xor(g, off);
        g += tl[STOP_ * Td + tags[bS + len - 1]];
        if (lane == 0) wsg[b] = g;
    }

    // ---- runtime-detect row_ror direction (validated R9-R12) ----
    const int p = lane & 15;
    const int qd = __builtin_amdgcn_mov_dpp(p, 0x121, 0xF, 0xF, false); // row_ror:1
    const int d = (qd == ((p + 1) & 15)) ? 1 : -1;
    const int g16 = lane >> 4;
    const int r0 = g16 & 3;                          // own 16-block (3 = idle lanes)

    // ---- runtime-detect permlane dup mapping (R10/R15-validated method) ----
    int ma = lane, mb = lane;
    SWAP32(ma, mb);
    int m0 = ma, m1 = ma; SWAP16(m0, m1);
    int m2 = mb, m3 = mb; SWAP16(m2, m3);
    const int ro0 = rfl_i(m0) >> 4, ro1 = rfl_i(m1) >> 4;
    const int ro2 = rfl_i(m2) >> 4, ro3 = rfl_i(m3) >> 4;
    const int want1 = (g16 + 1) % 3;                 // slot1 block per lane group
    const int want2 = (g16 + 2) % 3;                 // slot2 block per lane group
    const bool q11 = (ro1 == want1), q12 = (ro2 == want1), q13 = (ro3 == want1);
    const bool q21 = (ro1 == want2), q22 = (ro2 == want2), q23 = (ro3 == want2);
    (void)ro0;                                       // base of selects is _f0

    // ---- E (fwd) / E^T (bwd) in gather-permuted scalar order (R12 verbatim) ----
    float eA0[16], eA1[16], eA2[16];
#pragma unroll
    for (int h = 0; h < 3; ++h) {
        float* dst = (h == 0) ? eA0 : (h == 1) ? eA1 : eA2;
        const int blk = 16 * ((r0 + h) % 3);
#pragma unroll
        for (int i = 0; i < 16; ++i) {
            const int cc = blk + ((p + d * i) & 15);
            float e0 = 0.f;
            if (!isb) { if (lane < NTAG) e0 = __expf(tl[lane * Td + cc]); }
            else      { if (lane < Td)   e0 = __expf(tl[cc * Td + lane]); }
            dst[i] = e0;
        }
    }

    // ---- chain init ----
    const int lidx = (lane < Td) ? lane : 0;
    const float* frow = feats + bS * Td;
    const int Fh = (len + 1) >> 1;
    const int act = rfl_i(isb ? (len - Fh) : (Fh - 1));
    const int it0 = isb ? (len - 1) : 0;

    float einit;
    if (!isb) einit = (lane < NTAG) ? __expf(tl[lane * Td + START_]) : 0.f;
    else      einit = (lane < Td)   ? __expf(tl[STOP_ * Td + lane])  : 0.f;

    float v  = __expf(frow[(size_t)it0 * Td + lidx]) * einit;
    float uf = einit;                 // bwd act==0 case: wstop
    int L = 0, kx; float sc;
    { int kb = rfl_i(__float_as_int(v)); kx = ((kb >> 23) & 0xFF) - 127;
      sc = __int_as_float((127 - kx) << 23); }

    // ---- emission prefetch: 8 slots, PRE-EXP'd; uniform ptr + scalar advance ----
    auto eidx0 = [&](int s) -> int {
        if (!isb) { int t = 1 + s; return t < Sd ? t : (Sd - 1); }
        int t = len - 2 - s; return t > 0 ? t : 0;
    };
    float pf0 = __expf(frow[(size_t)eidx0(0) * Td + lidx]);
    float pf1 = __expf(frow[(size_t)eidx0(1) * Td + lidx]);
    float pf2 = __expf(frow[(size_t)eidx0(2) * Td + lidx]);
    float pf3 = __expf(frow[(size_t)eidx0(3) * Td + lidx]);
    float pf4 = __expf(frow[(size_t)eidx0(4) * Td + lidx]);
    float pf5 = __expf(frow[(size_t)eidx0(5) * Td + lidx]);
    float pf6 = __expf(frow[(size_t)eidx0(6) * Td + lidx]);
    float pf7 = __expf(frow[(size_t)eidx0(7) * Td + lidx]);
    int tn = eidx0(8);
    const float* pcur = frow + (size_t)tn * Td;
    const int sAdv = isb ? -Td : Td;
    const int sInc = isb ? -1 : 1;
    const int tmax = Sd - 1;

    // phases: L,L,L,H repeating (renorm every 4th step; <=3 pending steps,
    // growth <= 2^19.3/step -> bounded < 2^90, no overflow possible)
    int s = 0;
    while (s + 8 <= act) {
        STEP_L(pf0); pf0 = __expf(pcur[lidx]); ADVP();
        STEP_L(pf1); pf1 = __expf(pcur[lidx]); ADVP();
        STEP_L(pf2); pf2 = __expf(pcur[lidx]); ADVP();
        STEP_H(pf3); pf3 = __expf(pcur[lidx]); ADVP();
        STEP_L(pf4); pf4 = __expf(pcur[lidx]); ADVP();
        STEP_L(pf5); pf5 = __expf(pcur[lidx]); ADVP();
        STEP_L(pf6); pf6 = __expf(pcur[lidx]); ADVP();
        STEP_H(pf7); pf7 = __expf(pcur[lidx]); ADVP();
        s += 8;
    }
    if (s < act) { STEP_L(pf0); ++s; }
    if (s < act) { STEP_L(pf1); ++s; }
    if (s < act) { STEP_L(pf2); ++s; }
    if (s < act) { STEP_H(pf3); ++s; }
    if (s < act) { STEP_L(pf4); ++s; }
    if (s < act) { STEP_L(pf5); ++s; }
    if (s < act) { STEP_L(pf6); ++s; }

    // ---- publish meeting pieces (component-major for coalesced combine) ----
    if (!isb) {
        if (lane < Td) wsv[lane * Bn + b] = v;
        if (lane == 0) wsLF[b] = L;
    } else {
        if (lane < Td) wsu[lane * Bn + b] = uf;
        if (lane == 0) wsLB[b] = L;
    }
}

__launch_bounds__(64)
__global__ void crf_combine(const float* __restrict__ wsv,
                            const float* __restrict__ wsu,
                            const int* __restrict__ wsLF,
                            const int* __restrict__ wsLB,
                            const float* __restrict__ wsg,
                            float* __restrict__ out, int Bn)
{
    const int b = blockIdx.x * 64 + threadIdx.x;
    if (b >= Bn) return;
    float dot = 0.f;
#pragma unroll
    for (int j = 0; j < Td; ++j)
        dot += wsv[j * Bn + b] * wsu[j * Bn + b];
    const float ln2 = 0.6931471805599453f;
    out[b] = (float)(wsLF[b] + wsLB[b]) * ln2 + __logf(dot) - wsg[b];
}

extern "C" void kernel_launch(void* const* d_in, const int* in_sizes, int n_in,
                              void* d_out, int out_size, void* d_ws, size_t ws_size,
                              hipStream_t stream) {
    const float* feats = (const float*)d_in[0];
    const float* masks = (const float*)d_in[1];
    const int*   tags  = (const int*)d_in[2];
    const float* trans = (const float*)d_in[3];
    float* outp = (float*)d_out;

    const int Bn = in_sizes[1] / Sd;                 // B = 512

    float* wsv  = (float*)d_ws;                      // [48][Bn]
    float* wsu  = wsv + (size_t)Td * Bn;             // [48][Bn]
    int*   wsLF = (int*)(wsu + (size_t)Td * Bn);     // [Bn]
    int*   wsLB = wsLF + Bn;                         // [Bn]
    float* wsg  = (float*)(wsLB + Bn);               // [Bn]

    crf_chains<<<dim3(2 * Bn), dim3(64), 0, stream>>>(feats, masks, tags, trans,
                                                      wsv, wsu, wsLF, wsLB, wsg, Bn);
    crf_combine<<<dim3((Bn + 63) / 64), dim3(64), 0, stream>>>(wsv, wsu, wsLF, wsLB, wsg, outp, Bn);
}